// Round 4
// baseline (1049.237 us; speedup 1.0000x reference)
//
#include <hip/hip_runtime.h>
#include <hip/hip_bf16.h>
#include <math.h>

// Problem constants (CrossAttention_29678224015453)
#define B_   2
#define S_   4096
#define H_   8
#define D_   160
#define QD_  1280
#define SCALE 0.07905694150420949f   // 160^-0.5
#define LOG2E 1.4426950408889634f

typedef unsigned short ushort_t;
typedef __attribute__((ext_vector_type(8))) short short8;
typedef __attribute__((ext_vector_type(4))) float f32x4;

#define MFMA16(a, b, c) __builtin_amdgcn_mfma_f32_16x16x32_bf16(a, b, c, 0, 0, 0)

__device__ __forceinline__ ushort_t f2bf(float f) {
  unsigned u = __float_as_uint(f);
  u += 0x7fffu + ((u >> 16) & 1u);   // RNE
  return (ushort_t)(u >> 16);
}
// round-half-up bf16 (2 VALU ops)
__device__ __forceinline__ ushort_t f2bf_fast(float f) {
  return (ushort_t)((__float_as_uint(f) + 0x8000u) >> 16);
}

// async 16B global->LDS; LDS dest = wave-uniform base + lane*16
__device__ __forceinline__ void gload_lds16(const ushort_t* g, ushort_t* l) {
  __builtin_amdgcn_global_load_lds(
      (const __attribute__((address_space(1))) unsigned int*)(g),
      (__attribute__((address_space(3))) unsigned int*)(l), 16, 0, 0);
}

// DPP reduce over the 16-lane row group
template <int CTRL>
__device__ __forceinline__ float dpp_mov(float x) {
  return __int_as_float(
      __builtin_amdgcn_update_dpp(0, __float_as_int(x), CTRL, 0xF, 0xF, true));
}
__device__ __forceinline__ float row_sum16(float x) {
  x += dpp_mov<0xB1>(x);    // quad_perm xor1
  x += dpp_mov<0x4E>(x);    // quad_perm xor2
  x += dpp_mov<0x124>(x);   // row_ror:4
  x += dpp_mov<0x128>(x);   // row_ror:8
  return x;
}

// ---------------------------------------------------------------------------
// Transpose+convert (fused x & c): src fp32 [b][C=1280][S] -> dst bf16 [b][S][C]
// z: 0,1 -> hidden_states/batch z; 2,3 -> context/batch z-2.
// ---------------------------------------------------------------------------
__global__ __launch_bounds__(256) void transpose_cvt2(
    const float* __restrict__ xs, const float* __restrict__ cs,
    ushort_t* __restrict__ Xt, ushort_t* __restrict__ Ct)
{
  const int z = blockIdx.z;
  const int b = z & 1;
  const float* src = (z < 2) ? xs : cs;
  ushort_t* dst    = (z < 2) ? Xt : Ct;
  const int s0 = blockIdx.x * 32;
  const int c0 = blockIdx.y * 32;
  __shared__ float T[32][33];
  const int t = threadIdx.x;
  const int sl = t & 31, cr = t >> 5;
#pragma unroll
  for (int i = 0; i < 4; ++i)
    T[cr + i * 8][sl] = src[((size_t)b * QD_ + c0 + cr + i * 8) * S_ + s0 + sl];
  __syncthreads();
  const int cl = (t & 7) * 4, sr = t >> 3;
  ushort4 v;
  v.x = f2bf(T[cl + 0][sr]);
  v.y = f2bf(T[cl + 1][sr]);
  v.z = f2bf(T[cl + 2][sr]);
  v.w = f2bf(T[cl + 3][sr]);
  *(ushort4*)(dst + ((size_t)b * S_ + s0 + sr) * QD_ + c0 + cl) = v;
}

// ---------------------------------------------------------------------------
// Weight convert fp32 -> bf16 (4 matrices, blockIdx.y selects)
// ---------------------------------------------------------------------------
__global__ __launch_bounds__(256) void cvt_w(
    const float* __restrict__ w0, const float* __restrict__ w1,
    const float* __restrict__ w2, const float* __restrict__ w3,
    ushort_t* __restrict__ o0, ushort_t* __restrict__ o1,
    ushort_t* __restrict__ o2, ushort_t* __restrict__ o3)
{
  const int which = blockIdx.y;
  const float* s = which == 0 ? w0 : which == 1 ? w1 : which == 2 ? w2 : w3;
  ushort_t* d    = which == 0 ? o0 : which == 1 ? o1 : which == 2 ? o2 : o3;
  const size_t i = ((size_t)blockIdx.x * 256 + threadIdx.x) * 4;
  const float4 f = *(const float4*)(s + i);
  ushort4 v;
  v.x = f2bf(f.x); v.y = f2bf(f.y); v.z = f2bf(f.z); v.w = f2bf(f.w);
  *(ushort4*)(d + i) = v;
}

// ---------------------------------------------------------------------------
// Shared GEMM tile geometry: 128x128 tile, BK=32, 4 waves 2x2, wave 64x64.
// Double-buffered LDS + counted-wait pipeline (R3, unchanged).
// ---------------------------------------------------------------------------
#define GBM 128
#define GBN 128
#define GBK 32

#define GEMM_STAGE(tt, p, Abp, Bbp, Kv)                                        \
  {                                                                            \
    const int k0s = (tt) * GBK;                                                \
    _Pragma("unroll")                                                          \
    for (int i = 0; i < 2; ++i) {                                              \
      const int G = (i * 4 + wid) * 64 + lane;                                 \
      const int r = G >> 2, sl = G & 3;                                        \
      const int g = sl ^ (r & 3);                                              \
      gload_lds16(Abp + (size_t)(m0 + r) * (Kv) + k0s + g * 8,                 \
                  &As[p][(i * 4 + wid) * 512]);                                \
      gload_lds16(Bbp + (size_t)(n0 + r) * (Kv) + k0s + g * 8,                 \
                  &Bs[p][(i * 4 + wid) * 512]);                                \
    }                                                                          \
  }

// ---------------------------------------------------------------------------
// Fused Q/K/V projection GEMMs. grid (320, 1, 6): z -> {Q,K,V} x {b}.
// ---------------------------------------------------------------------------
__global__ __launch_bounds__(256) void gemm_qkv(
    const ushort_t* __restrict__ Xt, const ushort_t* __restrict__ Ct,
    const ushort_t* __restrict__ Wqb, const ushort_t* __restrict__ Wkb,
    const ushort_t* __restrict__ Wvb,
    ushort_t* __restrict__ q_ws, ushort_t* __restrict__ k_ws,
    ushort_t* __restrict__ v_ws)
{
  const size_t PB = (size_t)S_ * QD_;
  const int which = blockIdx.z >> 1, b = blockIdx.z & 1;
  const ushort_t* Ab;
  const ushort_t* Bb;
  ushort_t* Cb;
  int Nv, nx, cm, cn;
  if (which == 0) {
    Ab = Xt + (size_t)b * PB; Bb = Wqb; Cb = q_ws + (size_t)b * PB;
    Nv = QD_; nx = 10; cm = 4; cn = 10;
  } else if (which == 1) {
    Ab = Ct + (size_t)b * PB; Bb = Wkb; Cb = k_ws + (size_t)b * PB;
    Nv = QD_; nx = 10; cm = 4; cn = 10;
  } else {
    Ab = Wvb; Bb = Ct + (size_t)b * PB; Cb = v_ws + (size_t)b * PB;
    Nv = S_; nx = 32; cm = 5; cn = 8;
  }
  // XCD-chunked decode within the 320-block slice
  const int tiles_x = nx / cn;
  const int orig = blockIdx.x;
  const int xcd = orig & 7, idx = orig >> 3;
  const int trow = xcd / tiles_x, tcol = xcd - trow * tiles_x;
  const int m0 = (trow * cm + idx / cn) * GBM;
  const int n0 = (tcol * cn + idx % cn) * GBN;

  __shared__ ushort_t As[2][GBM * GBK];   // 2 x 8 KB
  __shared__ ushort_t Bs[2][GBN * GBK];   // 2 x 8 KB

  const int t = threadIdx.x;
  const int wid = t >> 6, lane = t & 63;
  const int l16 = lane & 15, quad = lane >> 4;
  const int wm = (wid >> 1) * 64, wn = (wid & 1) * 64;

  f32x4 acc[4][4];
#pragma unroll
  for (int i = 0; i < 4; ++i)
#pragma unroll
    for (int j = 0; j < 4; ++j) acc[i][j] = {0.f, 0.f, 0.f, 0.f};

  const int NIT = QD_ / GBK;   // 40
  GEMM_STAGE(0, 0, Ab, Bb, QD_);
  for (int it = 0; it < NIT; ++it) {
    asm volatile("s_waitcnt vmcnt(0)" ::: "memory");
    __builtin_amdgcn_sched_barrier(0);
    __builtin_amdgcn_s_barrier();
    __builtin_amdgcn_sched_barrier(0);
    if (it + 1 < NIT) {
      GEMM_STAGE(it + 1, (it + 1) & 1, Ab, Bb, QD_);
      __builtin_amdgcn_sched_barrier(0);
    }
    const int p = it & 1;
    short8 af[4], bfr[4];
#pragma unroll
    for (int mt = 0; mt < 4; ++mt) {
      const int r = wm + mt * 16 + l16;
      af[mt] = *(const short8*)&As[p][r * 32 + ((quad ^ (r & 3)) << 3)];
    }
#pragma unroll
    for (int nt = 0; nt < 4; ++nt) {
      const int r = wn + nt * 16 + l16;
      bfr[nt] = *(const short8*)&Bs[p][r * 32 + ((quad ^ (r & 3)) << 3)];
    }
#pragma unroll
    for (int mt = 0; mt < 4; ++mt)
#pragma unroll
      for (int nt = 0; nt < 4; ++nt)
        acc[mt][nt] = MFMA16(af[mt], bfr[nt], acc[mt][nt]);
  }

  // bf16 epilogue
#pragma unroll
  for (int mt = 0; mt < 4; ++mt)
#pragma unroll
    for (int r = 0; r < 4; ++r) {
      const int row = m0 + wm + mt * 16 + quad * 4 + r;
      ushort_t* cr = Cb + (size_t)row * Nv + n0 + wn + l16;
#pragma unroll
      for (int nt = 0; nt < 4; ++nt) cr[nt * 16] = f2bf_fast(acc[mt][nt][r]);
    }
}

// ---------------------------------------------------------------------------
// Generic pipelined GEMM (used for the output projection, mode 1: fp32+bias).
// ---------------------------------------------------------------------------
__global__ __launch_bounds__(256) void gemm_mfma(
    const ushort_t* __restrict__ A, const ushort_t* __restrict__ B,
    void* __restrict__ Cp, const float* __restrict__ bias,
    int M, int N, int K, int mode,
    size_t strideA, size_t strideB, size_t strideC,
    int cm, int cn)
{
  const int bz = blockIdx.z;
  const int nx = gridDim.x;
  const int tiles_x = nx / cn;
  const int orig = blockIdx.x + nx * blockIdx.y;
  const int xcd = orig & 7;
  const int idx = orig >> 3;
  const int trow = xcd / tiles_x, tcol = xcd - trow * tiles_x;
  const int m0 = (trow * cm + idx / cn) * GBM;
  const int n0 = (tcol * cn + idx % cn) * GBN;

  const ushort_t* __restrict__ Ab = A + (size_t)bz * strideA;
  const ushort_t* __restrict__ Bb = B + (size_t)bz * strideB;

  __shared__ ushort_t As[2][GBM * GBK];
  __shared__ ushort_t Bs[2][GBN * GBK];

  const int t = threadIdx.x;
  const int wid = t >> 6, lane = t & 63;
  const int l16 = lane & 15, quad = lane >> 4;
  const int wm = (wid >> 1) * 64, wn = (wid & 1) * 64;

  f32x4 acc[4][4];
#pragma unroll
  for (int i = 0; i < 4; ++i)
#pragma unroll
    for (int j = 0; j < 4; ++j) acc[i][j] = {0.f, 0.f, 0.f, 0.f};

  const int NIT = K / GBK;
  GEMM_STAGE(0, 0, Ab, Bb, K);
  for (int it = 0; it < NIT; ++it) {
    asm volatile("s_waitcnt vmcnt(0)" ::: "memory");
    __builtin_amdgcn_sched_barrier(0);
    __builtin_amdgcn_s_barrier();
    __builtin_amdgcn_sched_barrier(0);
    if (it + 1 < NIT) {
      GEMM_STAGE(it + 1, (it + 1) & 1, Ab, Bb, K);
      __builtin_amdgcn_sched_barrier(0);
    }
    const int p = it & 1;
    short8 af[4], bfr[4];
#pragma unroll
    for (int mt = 0; mt < 4; ++mt) {
      const int r = wm + mt * 16 + l16;
      af[mt] = *(const short8*)&As[p][r * 32 + ((quad ^ (r & 3)) << 3)];
    }
#pragma unroll
    for (int nt = 0; nt < 4; ++nt) {
      const int r = wn + nt * 16 + l16;
      bfr[nt] = *(const short8*)&Bs[p][r * 32 + ((quad ^ (r & 3)) << 3)];
    }
#pragma unroll
    for (int mt = 0; mt < 4; ++mt)
#pragma unroll
      for (int nt = 0; nt < 4; ++nt)
        acc[mt][nt] = MFMA16(af[mt], bfr[nt], acc[mt][nt]);
  }

  if (mode == 0) {
    ushort_t* C = (ushort_t*)Cp + (size_t)bz * strideC;
#pragma unroll
    for (int mt = 0; mt < 4; ++mt)
#pragma unroll
      for (int r = 0; r < 4; ++r) {
        const int row = m0 + wm + mt * 16 + quad * 4 + r;
        ushort_t* cr = C + (size_t)row * N + n0 + wn + l16;
#pragma unroll
        for (int nt = 0; nt < 4; ++nt) cr[nt * 16] = f2bf_fast(acc[mt][nt][r]);
      }
  } else {
    float* C = (float*)Cp + (size_t)bz * strideC;
#pragma unroll
    for (int mt = 0; mt < 4; ++mt)
#pragma unroll
      for (int r = 0; r < 4; ++r) {
        const int row = m0 + wm + mt * 16 + quad * 4 + r;
        const float bv = bias[row];
        float* cr = C + (size_t)row * N + n0 + wn + l16;
#pragma unroll
        for (int nt = 0; nt < 4; ++nt) cr[nt * 16] = acc[mt][nt][r] + bv;
      }
  }
}

// ---------------------------------------------------------------------------
// MFMA flash attention, TQ=128, 4 waves x 32 q-rows.
// R4: V is NOT staged in LDS — PV reads V directly from global. After R2's
// XCD swizzle the per-chunk V-tile (20KB) is L1-resident and the head's K/V
// is L2-resident (FETCH=35MB proved it), so LDS staging of V was pure
// LDS-pipe overhead (m169 lesson). LDS reads/wave-chunk drop 44->24 and the
// LDS block shrinks 63488->39936B -> 3-4 blocks/CU (launch_bounds 256,3).
// Sync per chunk: [bar A: Kt(t) valid] QK^T -> [bar B: Kt reads done] ->
// stage Kt(t+1) DMA -> softmax/P/ap -> PV (direct V) -> vmcnt(0) (nearly
// free: V-load in-order retirement means the DMA is already drained) -> barA.
// ---------------------------------------------------------------------------
#define TQ 128
#define TK 64
#define KTSTR 168   // ushorts (21 granules), 84 dw = 20 mod 32
#define PSTR  72    // ushorts, 36 dw = 4 mod 32

__global__ __launch_bounds__(256, 3) void flash_attn_mfma(
    const ushort_t* __restrict__ qws, const ushort_t* __restrict__ kws,
    const ushort_t* __restrict__ vws, const float* __restrict__ mask,
    ushort_t* __restrict__ attn_out)
{
  const int b  = blockIdx.z;
  // ---- XCD swizzle: 256 blocks/z = 8 XCDs x 32 q-blocks; head = XCD.
  const int orig = blockIdx.x + 32 * blockIdx.y;      // 0..255
  const int swz  = ((orig & 7) << 5) | (orig >> 3);
  const int q0 = (swz & 31) * TQ;
  const int h  = swz >> 5;
  const int t  = threadIdx.x;
  const int wid  = t >> 6;
  const int lane = t & 63;
  const int l16  = lane & 15;
  const int quad = lane >> 4;

  __shared__ __align__(16) ushort_t smem[19968];   // 39936 B
  ushort_t* Kt = smem;                 // [64][168]
  ushort_t* Pp = smem + 1344 * 8;      // [4][32][72], column-swizzled

  // ---- K staging offsets: issue jj covers granules (jj*4+wid)*64+lane
  int goff[6];
#pragma unroll
  for (int jj = 0; jj < 6; ++jj) {
    const int j = jj * 4 + wid;
    int off = 0;
    if (j < 21) {
      const int slot = j * 64 + lane;
      const int r = slot / 21, c = slot - r * 21;
      off = (c < 20) ? r * QD_ + c * 8 : 0;
    }
    goff[jj] = off;
  }

  const ushort_t* kg = kws + (size_t)b * S_ * QD_ + h * D_;    // +kp0*QD_ per chunk
  const ushort_t* vg = vws + ((size_t)b * QD_ + h * D_) * S_;  // +kp0 per chunk
  // per-thread V base: row l16 (of each 16-row group), col quad*8
  const ushort_t* vtb = vg + (size_t)l16 * S_ + quad * 8;

  // ---- Q fragments in registers: A[m=l16][k=dc*32+quad*8+j], 2 m-tiles
  short8 aq[2][5];
#pragma unroll
  for (int mt = 0; mt < 2; ++mt) {
    const ushort_t* qrow =
        qws + ((size_t)(b * S_ + q0 + wid * 32 + mt * 16 + l16)) * QD_ + h * D_;
#pragma unroll
    for (int dc = 0; dc < 5; ++dc)
      aq[mt][dc] = *(const short8*)(qrow + dc * 32 + quad * 8);
  }

  // ---- prologue: stage Kt(0), drain, barrier
#pragma unroll
  for (int jj = 0; jj < 6; ++jj) {
    const int j = jj * 4 + wid;
    if (j < 21) gload_lds16(kg + goff[jj], &smem[(size_t)j * 512]);
  }
  asm volatile("s_waitcnt vmcnt(0)" ::: "memory");
  __syncthreads();

  f32x4 Oa[2][10];
#pragma unroll
  for (int mt = 0; mt < 2; ++mt)
#pragma unroll
    for (int nt = 0; nt < 10; ++nt) Oa[mt][nt] = {0.f, 0.f, 0.f, 0.f};
  float lpart[2][4] = {{0.f, 0.f, 0.f, 0.f}, {0.f, 0.f, 0.f, 0.f}};
  const float SC2 = SCALE * LOG2E;

  const int pswz = quad << 4;          // P write-side column XOR
  const int prsw = (l16 >> 2) << 4;    // P read-side column XOR

  for (int kp0 = 0; kp0 < S_; kp0 += TK) {
    // ---- [bar A passed: Kt(t) valid for all waves]
    // mask loads early: latency hides under the QK^T MFMA cluster
    float mv[4];
#pragma unroll
    for (int c = 0; c < 4; ++c)
      mv[c] = mask[b * S_ + kp0 + c * 16 + l16] * LOG2E;

    // ---- QK^T: S[32q][64k] as 2x4 16x16 C-frags over 5 d-chunks
    f32x4 s[2][4];
#pragma unroll
    for (int mt = 0; mt < 2; ++mt)
#pragma unroll
      for (int c = 0; c < 4; ++c) s[mt][c] = {0.f, 0.f, 0.f, 0.f};
    __builtin_amdgcn_s_setprio(1);
#pragma unroll
    for (int dc = 0; dc < 5; ++dc) {
      short8 bb[4];
#pragma unroll
      for (int c = 0; c < 4; ++c)
        bb[c] = *(const short8*)&Kt[(c * 16 + l16) * KTSTR + dc * 32 + quad * 8];
#pragma unroll
      for (int mt = 0; mt < 2; ++mt)
#pragma unroll
        for (int c = 0; c < 4; ++c)
          s[mt][c] = MFMA16(aq[mt][dc], bb[c], s[mt][c]);
    }
    __builtin_amdgcn_s_setprio(0);

    // ---- bar B: every wave's Kt reads are consumed by its MFMAs above
    // (data-dep forces the lgkm waits), so a raw barrier suffices.
    __builtin_amdgcn_sched_barrier(0);
    __builtin_amdgcn_s_barrier();
    __builtin_amdgcn_sched_barrier(0);

    const int kn = kp0 + TK;
    // ---- stage Kt(t+1) DMA now; latency hides under softmax + PV
    if (kn < S_) {
      const ushort_t* kgn = kg + (size_t)kn * QD_;
#pragma unroll
      for (int jj = 0; jj < 6; ++jj) {
        const int j = jj * 4 + wid;
        if (j < 21) gload_lds16(kgn + goff[jj], &smem[(size_t)j * 512]);
      }
      __builtin_amdgcn_sched_barrier(0);   // pin issue before compute below
    }

    // ---- max-free softmax: p = exp2(s*SC2 + mv); per-lane l partials.
    // P[row][col] stored at col ^ (quad<<4)
    ushort_t* pw = Pp + wid * (32 * PSTR);
#pragma unroll
    for (int mt = 0; mt < 2; ++mt)
#pragma unroll
      for (int r = 0; r < 4; ++r) {
        const float p0 = exp2f(s[mt][0][r] * SC2 + mv[0]);
        const float p1 = exp2f(s[mt][1][r] * SC2 + mv[1]);
        const float p2 = exp2f(s[mt][2][r] * SC2 + mv[2]);
        const float p3 = exp2f(s[mt][3][r] * SC2 + mv[3]);
        lpart[mt][r] += (p0 + p1) + (p2 + p3);
        ushort_t* prow = pw + (mt * 16 + quad * 4 + r) * PSTR;
        prow[(pswz ^  0) + l16] = f2bf_fast(p0);
        prow[(pswz ^ 16) + l16] = f2bf_fast(p1);
        prow[(pswz ^ 32) + l16] = f2bf_fast(p2);
        prow[(pswz ^ 48) + l16] = f2bf_fast(p3);
      }

    // ---- PV A-frags from Pp (wave-private; LDS ops are in-order per wave)
    short8 ap[2][2];
#pragma unroll
    for (int mt = 0; mt < 2; ++mt) {
#pragma unroll
      for (int ks = 0; ks < 2; ++ks)
        ap[mt][ks] = *(const short8*)
            &Pp[wid * (32 * PSTR) + (mt * 16 + l16) * PSTR +
                ((ks * 32 + quad * 8) ^ prsw)];
    }

    // ---- PV: O[32q][160d] += P[32q][64k] * V[64k][160d], V direct from
    // global (L1/L2-resident). Per-wave pattern = 16 rows x 64B lines.
    const ushort_t* vb = vtb + kp0;
    __builtin_amdgcn_s_setprio(1);
#pragma unroll
    for (int nt = 0; nt < 10; ++nt) {
      const ushort_t* vr = vb + (size_t)(nt * 16) * S_;
      const short8 bv0 = *(const short8*)(vr);
      const short8 bv1 = *(const short8*)(vr + 32);
#pragma unroll
      for (int mt = 0; mt < 2; ++mt) {
        Oa[mt][nt] = MFMA16(ap[mt][0], bv0, Oa[mt][nt]);
        Oa[mt][nt] = MFMA16(ap[mt][1], bv1, Oa[mt][nt]);
      }
    }
    __builtin_amdgcn_s_setprio(0);

    // ---- bar A: drain the Kt(t+1) DMA (in-order vm retirement: the V loads
    // consumed above already forced it; vmcnt(0) is nearly free) then sync.
    asm volatile("s_waitcnt vmcnt(0)" ::: "memory");
    __builtin_amdgcn_sched_barrier(0);
    __builtin_amdgcn_s_barrier();
    __builtin_amdgcn_sched_barrier(0);
  }

  // ---- final l reduction, normalize, write bf16 attn[b][s][h*160+d]
#pragma unroll
  for (int mt = 0; mt < 2; ++mt)
#pragma unroll
    for (int r = 0; r < 4; ++r) {
      const float l = row_sum16(lpart[mt][r]);
      const float inv = 1.f / l;
      const int qq = q0 + wid * 32 + mt * 16 + quad * 4 + r;
      ushort_t* orow = attn_out + ((size_t)(b * S_ + qq)) * QD_ + h * D_;
#pragma unroll
      for (int nt = 0; nt < 10; ++nt)
        orow[nt * 16 + l16] = f2bf_fast(Oa[mt][nt][r] * inv);
    }
}

// ---------------------------------------------------------------------------
// Workspace: Xt | Ct | Wq/Wk/Wv/Wout bf16 | q_ws | k_ws | v_ws | attn_ws
// ---------------------------------------------------------------------------
extern "C" void kernel_launch(void* const* d_in, const int* in_sizes, int n_in,
                              void* d_out, int out_size, void* d_ws, size_t ws_size,
                              hipStream_t stream) {
  const float* x    = (const float*)d_in[0];
  const float* c    = (const float*)d_in[1];
  const float* mask = (const float*)d_in[2];
  const float* Wq   = (const float*)d_in[3];
  const float* Wk   = (const float*)d_in[4];
  const float* Wv   = (const float*)d_in[5];
  const float* Wout = (const float*)d_in[6];
  const float* bout = (const float*)d_in[7];
  float* out = (float*)d_out;

  const size_t PB   = (size_t)S_ * QD_;     // 5,242,880 per batch
  const size_t NELT = (size_t)B_ * PB;      // 10,485,760
  const size_t WN   = (size_t)QD_ * QD_;    // 1,638,400

  ushort_t* Xt    = (ushort_t*)d_ws;
  ushort_t* Ct    = Xt + NELT;
  ushort_t* Wqb   = Ct + NELT;
  ushort_t* Wkb   = Wqb + WN;
  ushort_t* Wvb   = Wkb + WN;
  ushort_t* Woutb = Wvb + WN;
  ushort_t* q_ws  = Woutb + WN;
  ushort_t* k_ws  = q_ws + NELT;
  ushort_t* v_ws  = k_ws + NELT;
  ushort_t* attn_ws = v_ws + NELT;

  const dim3 tgrid(S_ / 32, QD_ / 32, 2 * B_);      // (128, 40, 4)
  transpose_cvt2<<<tgrid, 256, 0, stream>>>(x, c, Xt, Ct);
  cvt_w<<<dim3(WN / 1024, 4, 1), 256, 0, stream>>>(Wq, Wk, Wv, Wout,
                                                   Wqb, Wkb, Wvb, Woutb);

  // Fused Q/K/V projections: one 1920-block dispatch
  gemm_qkv<<<dim3(320, 1, 6), 256, 0, stream>>>(Xt, Ct, Wqb, Wkb, Wvb,
                                                q_ws, k_ws, v_ws);

  const dim3 agrid(S_ / TQ, H_, B_);                // (32, 8, 2)
  flash_attn_mfma<<<agrid, 256, 0, stream>>>(q_ws, k_ws, v_ws, mask, attn_ws);

  // Output projection (pipelined, mode 1: fp32 + bias)
  const dim3 gv(S_ / GBN, QD_ / GBM, B_);           // (32, 10, 2)
  gemm_mfma<<<gv, 256, 0, stream>>>(Woutb, attn_ws, out, bout,
                                    QD_, S_, QD_, 1, 0, PB, PB, 5, 8);
}

// Round 5
// 710.590 us; speedup vs baseline: 1.4766x; 1.4766x over previous
//
#include <hip/hip_runtime.h>
#include <hip/hip_bf16.h>
#include <math.h>

// Problem constants (CrossAttention_29678224015453)
#define B_   2
#define S_   4096
#define H_   8
#define D_   160
#define QD_  1280
#define SCALE 0.07905694150420949f   // 160^-0.5
#define LOG2E 1.4426950408889634f

typedef unsigned short ushort_t;
typedef __attribute__((ext_vector_type(8))) short short8;
typedef __attribute__((ext_vector_type(4))) float f32x4;

#define MFMA16(a, b, c) __builtin_amdgcn_mfma_f32_16x16x32_bf16(a, b, c, 0, 0, 0)

__device__ __forceinline__ ushort_t f2bf(float f) {
  unsigned u = __float_as_uint(f);
  u += 0x7fffu + ((u >> 16) & 1u);   // RNE
  return (ushort_t)(u >> 16);
}
// round-half-up bf16 (2 VALU ops)
__device__ __forceinline__ ushort_t f2bf_fast(float f) {
  return (ushort_t)((__float_as_uint(f) + 0x8000u) >> 16);
}

// async 16B global->LDS; LDS dest = wave-uniform base + lane*16
__device__ __forceinline__ void gload_lds16(const ushort_t* g, ushort_t* l) {
  __builtin_amdgcn_global_load_lds(
      (const __attribute__((address_space(1))) unsigned int*)(g),
      (__attribute__((address_space(3))) unsigned int*)(l), 16, 0, 0);
}

// DPP reduce over the 16-lane row group
template <int CTRL>
__device__ __forceinline__ float dpp_mov(float x) {
  return __int_as_float(
      __builtin_amdgcn_update_dpp(0, __float_as_int(x), CTRL, 0xF, 0xF, true));
}
__device__ __forceinline__ float row_sum16(float x) {
  x += dpp_mov<0xB1>(x);    // quad_perm xor1
  x += dpp_mov<0x4E>(x);    // quad_perm xor2
  x += dpp_mov<0x124>(x);   // row_ror:4
  x += dpp_mov<0x128>(x);   // row_ror:8
  return x;
}

// ---------------------------------------------------------------------------
// Transpose+convert (fused x & c): src fp32 [b][C=1280][S] -> dst bf16 [b][S][C]
// z: 0,1 -> hidden_states/batch z; 2,3 -> context/batch z-2.
// ---------------------------------------------------------------------------
__global__ __launch_bounds__(256) void transpose_cvt2(
    const float* __restrict__ xs, const float* __restrict__ cs,
    ushort_t* __restrict__ Xt, ushort_t* __restrict__ Ct)
{
  const int z = blockIdx.z;
  const int b = z & 1;
  const float* src = (z < 2) ? xs : cs;
  ushort_t* dst    = (z < 2) ? Xt : Ct;
  const int s0 = blockIdx.x * 32;
  const int c0 = blockIdx.y * 32;
  __shared__ float T[32][33];
  const int t = threadIdx.x;
  const int sl = t & 31, cr = t >> 5;
#pragma unroll
  for (int i = 0; i < 4; ++i)
    T[cr + i * 8][sl] = src[((size_t)b * QD_ + c0 + cr + i * 8) * S_ + s0 + sl];
  __syncthreads();
  const int cl = (t & 7) * 4, sr = t >> 3;
  ushort4 v;
  v.x = f2bf(T[cl + 0][sr]);
  v.y = f2bf(T[cl + 1][sr]);
  v.z = f2bf(T[cl + 2][sr]);
  v.w = f2bf(T[cl + 3][sr]);
  *(ushort4*)(dst + ((size_t)b * S_ + s0 + sr) * QD_ + c0 + cl) = v;
}

// ---------------------------------------------------------------------------
// Weight convert fp32 -> bf16 (4 matrices, blockIdx.y selects)
// ---------------------------------------------------------------------------
__global__ __launch_bounds__(256) void cvt_w(
    const float* __restrict__ w0, const float* __restrict__ w1,
    const float* __restrict__ w2, const float* __restrict__ w3,
    ushort_t* __restrict__ o0, ushort_t* __restrict__ o1,
    ushort_t* __restrict__ o2, ushort_t* __restrict__ o3)
{
  const int which = blockIdx.y;
  const float* s = which == 0 ? w0 : which == 1 ? w1 : which == 2 ? w2 : w3;
  ushort_t* d    = which == 0 ? o0 : which == 1 ? o1 : which == 2 ? o2 : o3;
  const size_t i = ((size_t)blockIdx.x * 256 + threadIdx.x) * 4;
  const float4 f = *(const float4*)(s + i);
  ushort4 v;
  v.x = f2bf(f.x); v.y = f2bf(f.y); v.z = f2bf(f.z); v.w = f2bf(f.w);
  *(ushort4*)(d + i) = v;
}

// ---------------------------------------------------------------------------
// Shared GEMM tile geometry: 128x128 tile, BK=32, 4 waves 2x2, wave 64x64.
// Double-buffered LDS + counted-wait pipeline (R3, unchanged).
// ---------------------------------------------------------------------------
#define GBM 128
#define GBN 128
#define GBK 32

#define GEMM_STAGE(tt, p, Abp, Bbp, Kv)                                        \
  {                                                                            \
    const int k0s = (tt) * GBK;                                                \
    _Pragma("unroll")                                                          \
    for (int i = 0; i < 2; ++i) {                                              \
      const int G = (i * 4 + wid) * 64 + lane;                                 \
      const int r = G >> 2, sl = G & 3;                                        \
      const int g = sl ^ (r & 3);                                              \
      gload_lds16(Abp + (size_t)(m0 + r) * (Kv) + k0s + g * 8,                 \
                  &As[p][(i * 4 + wid) * 512]);                                \
      gload_lds16(Bbp + (size_t)(n0 + r) * (Kv) + k0s + g * 8,                 \
                  &Bs[p][(i * 4 + wid) * 512]);                                \
    }                                                                          \
  }

// ---------------------------------------------------------------------------
// Fused Q/K/V projection GEMMs. grid (320, 1, 6): z -> {Q,K,V} x {b}.
// ---------------------------------------------------------------------------
__global__ __launch_bounds__(256) void gemm_qkv(
    const ushort_t* __restrict__ Xt, const ushort_t* __restrict__ Ct,
    const ushort_t* __restrict__ Wqb, const ushort_t* __restrict__ Wkb,
    const ushort_t* __restrict__ Wvb,
    ushort_t* __restrict__ q_ws, ushort_t* __restrict__ k_ws,
    ushort_t* __restrict__ v_ws)
{
  const size_t PB = (size_t)S_ * QD_;
  const int which = blockIdx.z >> 1, b = blockIdx.z & 1;
  const ushort_t* Ab;
  const ushort_t* Bb;
  ushort_t* Cb;
  int Nv, nx, cm, cn;
  if (which == 0) {
    Ab = Xt + (size_t)b * PB; Bb = Wqb; Cb = q_ws + (size_t)b * PB;
    Nv = QD_; nx = 10; cm = 4; cn = 10;
  } else if (which == 1) {
    Ab = Ct + (size_t)b * PB; Bb = Wkb; Cb = k_ws + (size_t)b * PB;
    Nv = QD_; nx = 10; cm = 4; cn = 10;
  } else {
    Ab = Wvb; Bb = Ct + (size_t)b * PB; Cb = v_ws + (size_t)b * PB;
    Nv = S_; nx = 32; cm = 5; cn = 8;
  }
  // XCD-chunked decode within the 320-block slice
  const int tiles_x = nx / cn;
  const int orig = blockIdx.x;
  const int xcd = orig & 7, idx = orig >> 3;
  const int trow = xcd / tiles_x, tcol = xcd - trow * tiles_x;
  const int m0 = (trow * cm + idx / cn) * GBM;
  const int n0 = (tcol * cn + idx % cn) * GBN;

  __shared__ ushort_t As[2][GBM * GBK];   // 2 x 8 KB
  __shared__ ushort_t Bs[2][GBN * GBK];   // 2 x 8 KB

  const int t = threadIdx.x;
  const int wid = t >> 6, lane = t & 63;
  const int l16 = lane & 15, quad = lane >> 4;
  const int wm = (wid >> 1) * 64, wn = (wid & 1) * 64;

  f32x4 acc[4][4];
#pragma unroll
  for (int i = 0; i < 4; ++i)
#pragma unroll
    for (int j = 0; j < 4; ++j) acc[i][j] = {0.f, 0.f, 0.f, 0.f};

  const int NIT = QD_ / GBK;   // 40
  GEMM_STAGE(0, 0, Ab, Bb, QD_);
  for (int it = 0; it < NIT; ++it) {
    asm volatile("s_waitcnt vmcnt(0)" ::: "memory");
    __builtin_amdgcn_sched_barrier(0);
    __builtin_amdgcn_s_barrier();
    __builtin_amdgcn_sched_barrier(0);
    if (it + 1 < NIT) {
      GEMM_STAGE(it + 1, (it + 1) & 1, Ab, Bb, QD_);
      __builtin_amdgcn_sched_barrier(0);
    }
    const int p = it & 1;
    short8 af[4], bfr[4];
#pragma unroll
    for (int mt = 0; mt < 4; ++mt) {
      const int r = wm + mt * 16 + l16;
      af[mt] = *(const short8*)&As[p][r * 32 + ((quad ^ (r & 3)) << 3)];
    }
#pragma unroll
    for (int nt = 0; nt < 4; ++nt) {
      const int r = wn + nt * 16 + l16;
      bfr[nt] = *(const short8*)&Bs[p][r * 32 + ((quad ^ (r & 3)) << 3)];
    }
#pragma unroll
    for (int mt = 0; mt < 4; ++mt)
#pragma unroll
      for (int nt = 0; nt < 4; ++nt)
        acc[mt][nt] = MFMA16(af[mt], bfr[nt], acc[mt][nt]);
  }

  // bf16 epilogue
#pragma unroll
  for (int mt = 0; mt < 4; ++mt)
#pragma unroll
    for (int r = 0; r < 4; ++r) {
      const int row = m0 + wm + mt * 16 + quad * 4 + r;
      ushort_t* cr = Cb + (size_t)row * Nv + n0 + wn + l16;
#pragma unroll
      for (int nt = 0; nt < 4; ++nt) cr[nt * 16] = f2bf_fast(acc[mt][nt][r]);
    }
}

// ---------------------------------------------------------------------------
// Generic pipelined GEMM (used for the output projection, mode 1: fp32+bias).
// ---------------------------------------------------------------------------
__global__ __launch_bounds__(256) void gemm_mfma(
    const ushort_t* __restrict__ A, const ushort_t* __restrict__ B,
    void* __restrict__ Cp, const float* __restrict__ bias,
    int M, int N, int K, int mode,
    size_t strideA, size_t strideB, size_t strideC,
    int cm, int cn)
{
  const int bz = blockIdx.z;
  const int nx = gridDim.x;
  const int tiles_x = nx / cn;
  const int orig = blockIdx.x + nx * blockIdx.y;
  const int xcd = orig & 7;
  const int idx = orig >> 3;
  const int trow = xcd / tiles_x, tcol = xcd - trow * tiles_x;
  const int m0 = (trow * cm + idx / cn) * GBM;
  const int n0 = (tcol * cn + idx % cn) * GBN;

  const ushort_t* __restrict__ Ab = A + (size_t)bz * strideA;
  const ushort_t* __restrict__ Bb = B + (size_t)bz * strideB;

  __shared__ ushort_t As[2][GBM * GBK];
  __shared__ ushort_t Bs[2][GBN * GBK];

  const int t = threadIdx.x;
  const int wid = t >> 6, lane = t & 63;
  const int l16 = lane & 15, quad = lane >> 4;
  const int wm = (wid >> 1) * 64, wn = (wid & 1) * 64;

  f32x4 acc[4][4];
#pragma unroll
  for (int i = 0; i < 4; ++i)
#pragma unroll
    for (int j = 0; j < 4; ++j) acc[i][j] = {0.f, 0.f, 0.f, 0.f};

  const int NIT = K / GBK;
  GEMM_STAGE(0, 0, Ab, Bb, K);
  for (int it = 0; it < NIT; ++it) {
    asm volatile("s_waitcnt vmcnt(0)" ::: "memory");
    __builtin_amdgcn_sched_barrier(0);
    __builtin_amdgcn_s_barrier();
    __builtin_amdgcn_sched_barrier(0);
    if (it + 1 < NIT) {
      GEMM_STAGE(it + 1, (it + 1) & 1, Ab, Bb, K);
      __builtin_amdgcn_sched_barrier(0);
    }
    const int p = it & 1;
    short8 af[4], bfr[4];
#pragma unroll
    for (int mt = 0; mt < 4; ++mt) {
      const int r = wm + mt * 16 + l16;
      af[mt] = *(const short8*)&As[p][r * 32 + ((quad ^ (r & 3)) << 3)];
    }
#pragma unroll
    for (int nt = 0; nt < 4; ++nt) {
      const int r = wn + nt * 16 + l16;
      bfr[nt] = *(const short8*)&Bs[p][r * 32 + ((quad ^ (r & 3)) << 3)];
    }
#pragma unroll
    for (int mt = 0; mt < 4; ++mt)
#pragma unroll
      for (int nt = 0; nt < 4; ++nt)
        acc[mt][nt] = MFMA16(af[mt], bfr[nt], acc[mt][nt]);
  }

  if (mode == 0) {
    ushort_t* C = (ushort_t*)Cp + (size_t)bz * strideC;
#pragma unroll
    for (int mt = 0; mt < 4; ++mt)
#pragma unroll
      for (int r = 0; r < 4; ++r) {
        const int row = m0 + wm + mt * 16 + quad * 4 + r;
        ushort_t* cr = C + (size_t)row * N + n0 + wn + l16;
#pragma unroll
        for (int nt = 0; nt < 4; ++nt) cr[nt * 16] = f2bf_fast(acc[mt][nt][r]);
      }
  } else {
    float* C = (float*)Cp + (size_t)bz * strideC;
#pragma unroll
    for (int mt = 0; mt < 4; ++mt)
#pragma unroll
      for (int r = 0; r < 4; ++r) {
        const int row = m0 + wm + mt * 16 + quad * 4 + r;
        const float bv = bias[row];
        float* cr = C + (size_t)row * N + n0 + wn + l16;
#pragma unroll
        for (int nt = 0; nt < 4; ++nt) cr[nt * 16] = acc[mt][nt][r] + bv;
      }
  }
}

// ---------------------------------------------------------------------------
// MFMA flash attention, TQ=128, 4 waves x 32 q-rows.
// R5 = R4 structure with the spill confound removed: __launch_bounds__(256,2)
// (R4's (256,3) forced the allocator under the ~128-VGPR occupancy cliff ->
// 84 VGPR + accumulator spill -> 240MB scratch writes, 765us. The direct-V
// experiment itself was never tested.)
// V is NOT staged in LDS — PV reads V directly from global (L1/L2-resident
// after the XCD head-per-XCD swizzle; FETCH=35MB proved residency). LDS
// reads/wave-chunk drop 44->24; LDS block 63488->39936 B.
// Sync per chunk: [bar A: Kt(t) valid] QK^T -> [bar B: Kt reads done] ->
// stage Kt(t+1) DMA -> softmax/P/ap -> PV (direct V) -> vmcnt(0) -> bar A.
// ---------------------------------------------------------------------------
#define TQ 128
#define TK 64
#define KTSTR 168   // ushorts (21 granules), 84 dw = 20 mod 32
#define PSTR  72    // ushorts, 36 dw = 4 mod 32

__global__ __launch_bounds__(256, 2) void flash_attn_mfma(
    const ushort_t* __restrict__ qws, const ushort_t* __restrict__ kws,
    const ushort_t* __restrict__ vws, const float* __restrict__ mask,
    ushort_t* __restrict__ attn_out)
{
  const int b  = blockIdx.z;
  // ---- XCD swizzle: 256 blocks/z = 8 XCDs x 32 q-blocks; head = XCD.
  const int orig = blockIdx.x + 32 * blockIdx.y;      // 0..255
  const int swz  = ((orig & 7) << 5) | (orig >> 3);
  const int q0 = (swz & 31) * TQ;
  const int h  = swz >> 5;
  const int t  = threadIdx.x;
  const int wid  = t >> 6;
  const int lane = t & 63;
  const int l16  = lane & 15;
  const int quad = lane >> 4;

  __shared__ __align__(16) ushort_t smem[19968];   // 39936 B
  ushort_t* Kt = smem;                 // [64][168]
  ushort_t* Pp = smem + 1344 * 8;      // [4][32][72], column-swizzled

  // ---- K staging offsets: issue jj covers granules (jj*4+wid)*64+lane
  int goff[6];
#pragma unroll
  for (int jj = 0; jj < 6; ++jj) {
    const int j = jj * 4 + wid;
    int off = 0;
    if (j < 21) {
      const int slot = j * 64 + lane;
      const int r = slot / 21, c = slot - r * 21;
      off = (c < 20) ? r * QD_ + c * 8 : 0;
    }
    goff[jj] = off;
  }

  const ushort_t* kg = kws + (size_t)b * S_ * QD_ + h * D_;    // +kp0*QD_ per chunk
  const ushort_t* vg = vws + ((size_t)b * QD_ + h * D_) * S_;  // +kp0 per chunk
  // per-thread V base: row l16 (of each 16-row group), col quad*8
  const ushort_t* vtb = vg + (size_t)l16 * S_ + quad * 8;

  // ---- Q fragments in registers: A[m=l16][k=dc*32+quad*8+j], 2 m-tiles
  short8 aq[2][5];
#pragma unroll
  for (int mt = 0; mt < 2; ++mt) {
    const ushort_t* qrow =
        qws + ((size_t)(b * S_ + q0 + wid * 32 + mt * 16 + l16)) * QD_ + h * D_;
#pragma unroll
    for (int dc = 0; dc < 5; ++dc)
      aq[mt][dc] = *(const short8*)(qrow + dc * 32 + quad * 8);
  }

  // ---- prologue: stage Kt(0), drain, barrier
#pragma unroll
  for (int jj = 0; jj < 6; ++jj) {
    const int j = jj * 4 + wid;
    if (j < 21) gload_lds16(kg + goff[jj], &smem[(size_t)j * 512]);
  }
  asm volatile("s_waitcnt vmcnt(0)" ::: "memory");
  __syncthreads();

  f32x4 Oa[2][10];
#pragma unroll
  for (int mt = 0; mt < 2; ++mt)
#pragma unroll
    for (int nt = 0; nt < 10; ++nt) Oa[mt][nt] = {0.f, 0.f, 0.f, 0.f};
  float lpart[2][4] = {{0.f, 0.f, 0.f, 0.f}, {0.f, 0.f, 0.f, 0.f}};
  const float SC2 = SCALE * LOG2E;

  const int pswz = quad << 4;          // P write-side column XOR
  const int prsw = (l16 >> 2) << 4;    // P read-side column XOR

  for (int kp0 = 0; kp0 < S_; kp0 += TK) {
    // ---- [bar A passed: Kt(t) valid for all waves]
    // mask loads early: latency hides under the QK^T MFMA cluster
    float mv[4];
#pragma unroll
    for (int c = 0; c < 4; ++c)
      mv[c] = mask[b * S_ + kp0 + c * 16 + l16] * LOG2E;

    // ---- QK^T: S[32q][64k] as 2x4 16x16 C-frags over 5 d-chunks
    f32x4 s[2][4];
#pragma unroll
    for (int mt = 0; mt < 2; ++mt)
#pragma unroll
      for (int c = 0; c < 4; ++c) s[mt][c] = {0.f, 0.f, 0.f, 0.f};
    __builtin_amdgcn_s_setprio(1);
#pragma unroll
    for (int dc = 0; dc < 5; ++dc) {
      short8 bb[4];
#pragma unroll
      for (int c = 0; c < 4; ++c)
        bb[c] = *(const short8*)&Kt[(c * 16 + l16) * KTSTR + dc * 32 + quad * 8];
#pragma unroll
      for (int mt = 0; mt < 2; ++mt)
#pragma unroll
        for (int c = 0; c < 4; ++c)
          s[mt][c] = MFMA16(aq[mt][dc], bb[c], s[mt][c]);
    }
    __builtin_amdgcn_s_setprio(0);

    // ---- bar B: every wave's Kt reads are consumed by its MFMAs above
    // (data-dep forces the lgkm waits), so a raw barrier suffices.
    __builtin_amdgcn_sched_barrier(0);
    __builtin_amdgcn_s_barrier();
    __builtin_amdgcn_sched_barrier(0);

    const int kn = kp0 + TK;
    // ---- stage Kt(t+1) DMA now; latency hides under softmax + PV
    if (kn < S_) {
      const ushort_t* kgn = kg + (size_t)kn * QD_;
#pragma unroll
      for (int jj = 0; jj < 6; ++jj) {
        const int j = jj * 4 + wid;
        if (j < 21) gload_lds16(kgn + goff[jj], &smem[(size_t)j * 512]);
      }
      __builtin_amdgcn_sched_barrier(0);   // pin issue before compute below
    }

    // ---- max-free softmax: p = exp2(s*SC2 + mv); per-lane l partials.
    // P[row][col] stored at col ^ (quad<<4)
    ushort_t* pw = Pp + wid * (32 * PSTR);
#pragma unroll
    for (int mt = 0; mt < 2; ++mt)
#pragma unroll
      for (int r = 0; r < 4; ++r) {
        const float p0 = exp2f(s[mt][0][r] * SC2 + mv[0]);
        const float p1 = exp2f(s[mt][1][r] * SC2 + mv[1]);
        const float p2 = exp2f(s[mt][2][r] * SC2 + mv[2]);
        const float p3 = exp2f(s[mt][3][r] * SC2 + mv[3]);
        lpart[mt][r] += (p0 + p1) + (p2 + p3);
        ushort_t* prow = pw + (mt * 16 + quad * 4 + r) * PSTR;
        prow[(pswz ^  0) + l16] = f2bf_fast(p0);
        prow[(pswz ^ 16) + l16] = f2bf_fast(p1);
        prow[(pswz ^ 32) + l16] = f2bf_fast(p2);
        prow[(pswz ^ 48) + l16] = f2bf_fast(p3);
      }

    // ---- PV A-frags from Pp (wave-private; LDS ops are in-order per wave)
    short8 ap[2][2];
#pragma unroll
    for (int mt = 0; mt < 2; ++mt) {
#pragma unroll
      for (int ks = 0; ks < 2; ++ks)
        ap[mt][ks] = *(const short8*)
            &Pp[wid * (32 * PSTR) + (mt * 16 + l16) * PSTR +
                ((ks * 32 + quad * 8) ^ prsw)];
    }

    // ---- PV: O[32q][160d] += P[32q][64k] * V[64k][160d], V direct from
    // global (L1/L2-resident). Per-wave pattern = 16 rows x 64B lines.
    const ushort_t* vb = vtb + kp0;
    __builtin_amdgcn_s_setprio(1);
#pragma unroll
    for (int nt = 0; nt < 10; ++nt) {
      const ushort_t* vr = vb + (size_t)(nt * 16) * S_;
      const short8 bv0 = *(const short8*)(vr);
      const short8 bv1 = *(const short8*)(vr + 32);
#pragma unroll
      for (int mt = 0; mt < 2; ++mt) {
        Oa[mt][nt] = MFMA16(ap[mt][0], bv0, Oa[mt][nt]);
        Oa[mt][nt] = MFMA16(ap[mt][1], bv1, Oa[mt][nt]);
      }
    }
    __builtin_amdgcn_s_setprio(0);

    // ---- bar A: drain the Kt(t+1) DMA (in-order vm retirement: the V loads
    // consumed above already forced it; vmcnt(0) is nearly free) then sync.
    asm volatile("s_waitcnt vmcnt(0)" ::: "memory");
    __builtin_amdgcn_sched_barrier(0);
    __builtin_amdgcn_s_barrier();
    __builtin_amdgcn_sched_barrier(0);
  }

  // ---- final l reduction, normalize, write bf16 attn[b][s][h*160+d]
#pragma unroll
  for (int mt = 0; mt < 2; ++mt)
#pragma unroll
    for (int r = 0; r < 4; ++r) {
      const float l = row_sum16(lpart[mt][r]);
      const float inv = 1.f / l;
      const int qq = q0 + wid * 32 + mt * 16 + quad * 4 + r;
      ushort_t* orow = attn_out + ((size_t)(b * S_ + qq)) * QD_ + h * D_;
#pragma unroll
      for (int nt = 0; nt < 10; ++nt)
        orow[nt * 16 + l16] = f2bf_fast(Oa[mt][nt][r] * inv);
    }
}

// ---------------------------------------------------------------------------
// Workspace: Xt | Ct | Wq/Wk/Wv/Wout bf16 | q_ws | k_ws | v_ws | attn_ws
// ---------------------------------------------------------------------------
extern "C" void kernel_launch(void* const* d_in, const int* in_sizes, int n_in,
                              void* d_out, int out_size, void* d_ws, size_t ws_size,
                              hipStream_t stream) {
  const float* x    = (const float*)d_in[0];
  const float* c    = (const float*)d_in[1];
  const float* mask = (const float*)d_in[2];
  const float* Wq   = (const float*)d_in[3];
  const float* Wk   = (const float*)d_in[4];
  const float* Wv   = (const float*)d_in[5];
  const float* Wout = (const float*)d_in[6];
  const float* bout = (const float*)d_in[7];
  float* out = (float*)d_out;

  const size_t PB   = (size_t)S_ * QD_;     // 5,242,880 per batch
  const size_t NELT = (size_t)B_ * PB;      // 10,485,760
  const size_t WN   = (size_t)QD_ * QD_;    // 1,638,400

  ushort_t* Xt    = (ushort_t*)d_ws;
  ushort_t* Ct    = Xt + NELT;
  ushort_t* Wqb   = Ct + NELT;
  ushort_t* Wkb   = Wqb + WN;
  ushort_t* Wvb   = Wkb + WN;
  ushort_t* Woutb = Wvb + WN;
  ushort_t* q_ws  = Woutb + WN;
  ushort_t* k_ws  = q_ws + NELT;
  ushort_t* v_ws  = k_ws + NELT;
  ushort_t* attn_ws = v_ws + NELT;

  const dim3 tgrid(S_ / 32, QD_ / 32, 2 * B_);      // (128, 40, 4)
  transpose_cvt2<<<tgrid, 256, 0, stream>>>(x, c, Xt, Ct);
  cvt_w<<<dim3(WN / 1024, 4, 1), 256, 0, stream>>>(Wq, Wk, Wv, Wout,
                                                   Wqb, Wkb, Wvb, Woutb);

  // Fused Q/K/V projections: one 1920-block dispatch
  gemm_qkv<<<dim3(320, 1, 6), 256, 0, stream>>>(Xt, Ct, Wqb, Wkb, Wvb,
                                                q_ws, k_ws, v_ws);

  const dim3 agrid(S_ / TQ, H_, B_);                // (32, 8, 2)
  flash_attn_mfma<<<agrid, 256, 0, stream>>>(q_ws, k_ws, v_ws, mask, attn_ws);

  // Output projection (pipelined, mode 1: fp32 + bias)
  const dim3 gv(S_ / GBN, QD_ / GBM, B_);           // (32, 10, 2)
  gemm_mfma<<<gv, 256, 0, stream>>>(Woutb, attn_ws, out, bout,
                                    QD_, S_, QD_, 1, 0, PB, PB, 5, 8);
}

// Round 7
// 525.364 us; speedup vs baseline: 1.9972x; 1.3526x over previous
//
#include <hip/hip_runtime.h>
#include <hip/hip_bf16.h>
#include <math.h>

// Problem constants (CrossAttention_29678224015453)
#define B_   2
#define S_   4096
#define H_   8
#define D_   160
#define QD_  1280
#define SCALE 0.07905694150420949f   // 160^-0.5
#define LOG2E 1.4426950408889634f

typedef unsigned short ushort_t;
typedef __attribute__((ext_vector_type(8))) short short8;
typedef __attribute__((ext_vector_type(4))) float f32x4;

#define MFMA16(a, b, c) __builtin_amdgcn_mfma_f32_16x16x32_bf16(a, b, c, 0, 0, 0)

__device__ __forceinline__ ushort_t f2bf(float f) {
  unsigned u = __float_as_uint(f);
  u += 0x7fffu + ((u >> 16) & 1u);   // RNE
  return (ushort_t)(u >> 16);
}
// round-half-up bf16 (2 VALU ops)
__device__ __forceinline__ ushort_t f2bf_fast(float f) {
  return (ushort_t)((__float_as_uint(f) + 0x8000u) >> 16);
}

// async 16B global->LDS; LDS dest = wave-uniform base + lane*16
__device__ __forceinline__ void gload_lds16(const ushort_t* g, ushort_t* l) {
  __builtin_amdgcn_global_load_lds(
      (const __attribute__((address_space(1))) unsigned int*)(g),
      (__attribute__((address_space(3))) unsigned int*)(l), 16, 0, 0);
}

// DPP reduce over the 16-lane row group
template <int CTRL>
__device__ __forceinline__ float dpp_mov(float x) {
  return __int_as_float(
      __builtin_amdgcn_update_dpp(0, __float_as_int(x), CTRL, 0xF, 0xF, true));
}
__device__ __forceinline__ float row_sum16(float x) {
  x += dpp_mov<0xB1>(x);    // quad_perm xor1
  x += dpp_mov<0x4E>(x);    // quad_perm xor2
  x += dpp_mov<0x124>(x);   // row_ror:4
  x += dpp_mov<0x128>(x);   // row_ror:8
  return x;
}

// ---------------------------------------------------------------------------
// Transpose+convert (fused x & c): src fp32 [b][C=1280][S] -> dst bf16 [b][S][C]
// z: 0,1 -> hidden_states/batch z; 2,3 -> context/batch z-2.
// ---------------------------------------------------------------------------
__global__ __launch_bounds__(256) void transpose_cvt2(
    const float* __restrict__ xs, const float* __restrict__ cs,
    ushort_t* __restrict__ Xt, ushort_t* __restrict__ Ct)
{
  const int z = blockIdx.z;
  const int b = z & 1;
  const float* src = (z < 2) ? xs : cs;
  ushort_t* dst    = (z < 2) ? Xt : Ct;
  const int s0 = blockIdx.x * 32;
  const int c0 = blockIdx.y * 32;
  __shared__ float T[32][33];
  const int t = threadIdx.x;
  const int sl = t & 31, cr = t >> 5;
#pragma unroll
  for (int i = 0; i < 4; ++i)
    T[cr + i * 8][sl] = src[((size_t)b * QD_ + c0 + cr + i * 8) * S_ + s0 + sl];
  __syncthreads();
  const int cl = (t & 7) * 4, sr = t >> 3;
  ushort4 v;
  v.x = f2bf(T[cl + 0][sr]);
  v.y = f2bf(T[cl + 1][sr]);
  v.z = f2bf(T[cl + 2][sr]);
  v.w = f2bf(T[cl + 3][sr]);
  *(ushort4*)(dst + ((size_t)b * S_ + s0 + sr) * QD_ + c0 + cl) = v;
}

// ---------------------------------------------------------------------------
// Weight convert fp32 -> bf16 (4 matrices, blockIdx.y selects)
// ---------------------------------------------------------------------------
__global__ __launch_bounds__(256) void cvt_w(
    const float* __restrict__ w0, const float* __restrict__ w1,
    const float* __restrict__ w2, const float* __restrict__ w3,
    ushort_t* __restrict__ o0, ushort_t* __restrict__ o1,
    ushort_t* __restrict__ o2, ushort_t* __restrict__ o3)
{
  const int which = blockIdx.y;
  const float* s = which == 0 ? w0 : which == 1 ? w1 : which == 2 ? w2 : w3;
  ushort_t* d    = which == 0 ? o0 : which == 1 ? o1 : which == 2 ? o2 : o3;
  const size_t i = ((size_t)blockIdx.x * 256 + threadIdx.x) * 4;
  const float4 f = *(const float4*)(s + i);
  ushort4 v;
  v.x = f2bf(f.x); v.y = f2bf(f.y); v.z = f2bf(f.z); v.w = f2bf(f.w);
  *(ushort4*)(d + i) = v;
}

// ---------------------------------------------------------------------------
// Shared GEMM tile geometry: 128x128 tile, BK=32, 4 waves 2x2, wave 64x64.
// R6: TRIPLE-buffered LDS + counted vmcnt(4) (T4). R3's double-buffer waited
// stage(t) with vmcnt(0) only ONE compute phase (~150cy) after issue — less
// than L2/HBM latency, so every K-step exposed the residual. 3 buffers let
// stage(t+2) issue at iter t and be waited at iter t+2: two full phases of
// cover, and the wait is counted (vmcnt(4) = leave the newest stage in
// flight; per-wave stage = 4 vm ops, in-order retirement). Last iter peels
// to vmcnt(0). LDS 48KB -> 3 blocks/CU.
// ---------------------------------------------------------------------------
#define GBM 128
#define GBN 128
#define GBK 32

#define GEMM_STAGE(tt, p, Abp, Bbp, Kv)                                        \
  {                                                                            \
    const int k0s = (tt) * GBK;                                                \
    _Pragma("unroll")                                                          \
    for (int i = 0; i < 2; ++i) {                                              \
      const int G = (i * 4 + wid) * 64 + lane;                                 \
      const int r = G >> 2, sl = G & 3;                                        \
      const int g = sl ^ (r & 3);                                              \
      gload_lds16(Abp + (size_t)(m0 + r) * (Kv) + k0s + g * 8,                 \
                  &As[p][(i * 4 + wid) * 512]);                                \
      gload_lds16(Bbp + (size_t)(n0 + r) * (Kv) + k0s + g * 8,                 \
                  &Bs[p][(i * 4 + wid) * 512]);                                \
    }                                                                          \
  }

// Per-iteration body shared by both GEMM kernels (macro to keep LDS arrays
// local). Wait: vmcnt(4) normally (retire stage(it), keep stage(it+1) in
// flight), vmcnt(0) on the last iteration (only stage(NIT-1) outstanding).
#define GEMM_PIPE_ITER(it, NIT, Abp, Bbp, Kv)                                  \
  {                                                                            \
    if ((it) + 1 < (NIT)) {                                                    \
      asm volatile("s_waitcnt vmcnt(4)" ::: "memory");                         \
    } else {                                                                   \
      asm volatile("s_waitcnt vmcnt(0)" ::: "memory");                         \
    }                                                                          \
    __builtin_amdgcn_sched_barrier(0);                                         \
    __builtin_amdgcn_s_barrier();                                              \
    __builtin_amdgcn_sched_barrier(0);                                         \
    if ((it) + 2 < (NIT)) {                                                    \
      GEMM_STAGE((it) + 2, ((it) + 2) % 3, Abp, Bbp, Kv);                      \
      __builtin_amdgcn_sched_barrier(0);                                       \
    }                                                                          \
    const int p = (it) % 3;                                                    \
    short8 af[4], bfr[4];                                                      \
    _Pragma("unroll")                                                          \
    for (int mt = 0; mt < 4; ++mt) {                                           \
      const int r = wm + mt * 16 + l16;                                        \
      af[mt] = *(const short8*)&As[p][r * 32 + ((quad ^ (r & 3)) << 3)];       \
    }                                                                          \
    _Pragma("unroll")                                                          \
    for (int nt = 0; nt < 4; ++nt) {                                           \
      const int r = wn + nt * 16 + l16;                                        \
      bfr[nt] = *(const short8*)&Bs[p][r * 32 + ((quad ^ (r & 3)) << 3)];      \
    }                                                                          \
    _Pragma("unroll")                                                          \
    for (int mt = 0; mt < 4; ++mt)                                             \
      _Pragma("unroll")                                                        \
      for (int nt = 0; nt < 4; ++nt)                                           \
        acc[mt][nt] = MFMA16(af[mt], bfr[nt], acc[mt][nt]);                    \
  }

// ---------------------------------------------------------------------------
// Fused Q/K/V projection GEMMs. grid (320, 1, 6): z -> {Q,K,V} x {b}.
// ---------------------------------------------------------------------------
__global__ __launch_bounds__(256) void gemm_qkv(
    const ushort_t* __restrict__ Xt, const ushort_t* __restrict__ Ct,
    const ushort_t* __restrict__ Wqb, const ushort_t* __restrict__ Wkb,
    const ushort_t* __restrict__ Wvb,
    ushort_t* __restrict__ q_ws, ushort_t* __restrict__ k_ws,
    ushort_t* __restrict__ v_ws)
{
  const size_t PB = (size_t)S_ * QD_;
  const int which = blockIdx.z >> 1, b = blockIdx.z & 1;
  const ushort_t* Ab;
  const ushort_t* Bb;
  ushort_t* Cb;
  int Nv, nx, cm, cn;
  if (which == 0) {
    Ab = Xt + (size_t)b * PB; Bb = Wqb; Cb = q_ws + (size_t)b * PB;
    Nv = QD_; nx = 10; cm = 4; cn = 10;
  } else if (which == 1) {
    Ab = Ct + (size_t)b * PB; Bb = Wkb; Cb = k_ws + (size_t)b * PB;
    Nv = QD_; nx = 10; cm = 4; cn = 10;
  } else {
    Ab = Wvb; Bb = Ct + (size_t)b * PB; Cb = v_ws + (size_t)b * PB;
    Nv = S_; nx = 32; cm = 5; cn = 8;
  }
  // XCD-chunked decode within the 320-block slice
  const int tiles_x = nx / cn;
  const int orig = blockIdx.x;
  const int xcd = orig & 7, idx = orig >> 3;
  const int trow = xcd / tiles_x, tcol = xcd - trow * tiles_x;
  const int m0 = (trow * cm + idx / cn) * GBM;
  const int n0 = (tcol * cn + idx % cn) * GBN;

  __shared__ ushort_t As[3][GBM * GBK];   // 3 x 8 KB
  __shared__ ushort_t Bs[3][GBN * GBK];   // 3 x 8 KB

  const int t = threadIdx.x;
  const int wid = t >> 6, lane = t & 63;
  const int l16 = lane & 15, quad = lane >> 4;
  const int wm = (wid >> 1) * 64, wn = (wid & 1) * 64;

  f32x4 acc[4][4];
#pragma unroll
  for (int i = 0; i < 4; ++i)
#pragma unroll
    for (int j = 0; j < 4; ++j) acc[i][j] = {0.f, 0.f, 0.f, 0.f};

  const int NIT = QD_ / GBK;   // 40
  GEMM_STAGE(0, 0, Ab, Bb, QD_);
  GEMM_STAGE(1, 1, Ab, Bb, QD_);
  for (int it = 0; it < NIT; ++it) {
    GEMM_PIPE_ITER(it, NIT, Ab, Bb, QD_);
  }

  // bf16 epilogue
#pragma unroll
  for (int mt = 0; mt < 4; ++mt)
#pragma unroll
    for (int r = 0; r < 4; ++r) {
      const int row = m0 + wm + mt * 16 + quad * 4 + r;
      ushort_t* cr = Cb + (size_t)row * Nv + n0 + wn + l16;
#pragma unroll
      for (int nt = 0; nt < 4; ++nt) cr[nt * 16] = f2bf_fast(acc[mt][nt][r]);
    }
}

// ---------------------------------------------------------------------------
// Generic pipelined GEMM (used for the output projection, mode 1: fp32+bias).
// ---------------------------------------------------------------------------
__global__ __launch_bounds__(256) void gemm_mfma(
    const ushort_t* __restrict__ A, const ushort_t* __restrict__ B,
    void* __restrict__ Cp, const float* __restrict__ bias,
    int M, int N, int K, int mode,
    size_t strideA, size_t strideB, size_t strideC,
    int cm, int cn)
{
  const int bz = blockIdx.z;
  const int nx = gridDim.x;
  const int tiles_x = nx / cn;
  const int orig = blockIdx.x + nx * blockIdx.y;
  const int xcd = orig & 7;
  const int idx = orig >> 3;
  const int trow = xcd / tiles_x, tcol = xcd - trow * tiles_x;
  const int m0 = (trow * cm + idx / cn) * GBM;
  const int n0 = (tcol * cn + idx % cn) * GBN;

  const ushort_t* __restrict__ Ab = A + (size_t)bz * strideA;
  const ushort_t* __restrict__ Bb = B + (size_t)bz * strideB;

  __shared__ ushort_t As[3][GBM * GBK];
  __shared__ ushort_t Bs[3][GBN * GBK];

  const int t = threadIdx.x;
  const int wid = t >> 6, lane = t & 63;
  const int l16 = lane & 15, quad = lane >> 4;
  const int wm = (wid >> 1) * 64, wn = (wid & 1) * 64;

  f32x4 acc[4][4];
#pragma unroll
  for (int i = 0; i < 4; ++i)
#pragma unroll
    for (int j = 0; j < 4; ++j) acc[i][j] = {0.f, 0.f, 0.f, 0.f};

  const int NIT = K / GBK;
  GEMM_STAGE(0, 0, Ab, Bb, K);
  GEMM_STAGE(1, 1, Ab, Bb, K);
  for (int it = 0; it < NIT; ++it) {
    GEMM_PIPE_ITER(it, NIT, Ab, Bb, K);
  }

  if (mode == 0) {
    ushort_t* C = (ushort_t*)Cp + (size_t)bz * strideC;
#pragma unroll
    for (int mt = 0; mt < 4; ++mt)
#pragma unroll
      for (int r = 0; r < 4; ++r) {
        const int row = m0 + wm + mt * 16 + quad * 4 + r;
        ushort_t* cr = C + (size_t)row * N + n0 + wn + l16;
#pragma unroll
        for (int nt = 0; nt < 4; ++nt) cr[nt * 16] = f2bf_fast(acc[mt][nt][r]);
      }
  } else {
    float* C = (float*)Cp + (size_t)bz * strideC;
#pragma unroll
    for (int mt = 0; mt < 4; ++mt)
#pragma unroll
      for (int r = 0; r < 4; ++r) {
        const int row = m0 + wm + mt * 16 + quad * 4 + r;
        const float bv = bias[row];
        float* cr = C + (size_t)row * N + n0 + wn + l16;
#pragma unroll
        for (int nt = 0; nt < 4; ++nt) cr[nt * 16] = acc[mt][nt][r] + bv;
      }
  }
}

// ---------------------------------------------------------------------------
// MFMA flash attention, TQ=128 — REVERTED to the R3 version (239us, best
// measured). R5 proved direct-V loses (407us clean): PV's 16-line V gathers
// hit ~200+cyc L2 latency immediately before each MFMA with nothing to hide
// them. Staged V via LDS (12cyc ds_read) wins. Counted-vmcnt K/V pipeline,
// Pp column swizzle, setprio, hoisted mask, XCD head-per-XCD swizzle.
// LDS: 2816 granules * 16B + Pp 4*32*72*2 = 63488 B -> 2 blocks/CU.
// ---------------------------------------------------------------------------
#define TQ 128
#define TK 64
#define KTSTR 168   // ushorts (21 granules), 84 dw = 20 mod 32
#define VTSTR 72    // ushorts (9 granules),  36 dw = 4 mod 32
#define PSTR  72    // ushorts, 36 dw = 4 mod 32

__global__ __launch_bounds__(256, 2) void flash_attn_mfma(
    const ushort_t* __restrict__ qws, const ushort_t* __restrict__ kws,
    const ushort_t* __restrict__ vws, const float* __restrict__ mask,
    ushort_t* __restrict__ attn_out)
{
  const int b  = blockIdx.z;
  // ---- XCD swizzle: 256 blocks/z = 8 XCDs x 32 q-blocks; head = XCD.
  const int orig = blockIdx.x + 32 * blockIdx.y;      // 0..255
  const int swz  = ((orig & 7) << 5) | (orig >> 3);
  const int q0 = (swz & 31) * TQ;
  const int h  = swz >> 5;
  const int t  = threadIdx.x;
  const int wid  = t >> 6;
  const int lane = t & 63;
  const int l16  = lane & 15;
  const int quad = lane >> 4;

  __shared__ __align__(16) ushort_t smem[31744];
  ushort_t* Kt = smem;                 // [64][168]
  ushort_t* Vt = smem + 1344 * 8;      // [160][72]
  ushort_t* Pp = smem + 2816 * 8;      // [4][32][72], column-swizzled

  // ---- staging offsets: issue jj covers granules (jj*4+wid)*64+lane
  int goff[11];
#pragma unroll
  for (int jj = 0; jj < 11; ++jj) {
    const int j = jj * 4 + wid;
    const int slot = j * 64 + lane;
    int off;
    if (j < 21) {                       // K granule: row r, granule c of 21
      const int r = slot / 21, c = slot - r * 21;
      off = (c < 20) ? r * QD_ + c * 8 : 0;
    } else {                            // V granule: row r, granule c of 9
      const int vs = slot - 1344;
      const int r = vs / 9, c = vs - r * 9;
      off = (c < 8 && r < 160) ? r * S_ + c * 8 : 0;
    }
    goff[jj] = off;
  }

  const ushort_t* kg = kws + (size_t)b * S_ * QD_ + h * D_;          // +kp0*QD_ per chunk
  const ushort_t* vg = vws + ((size_t)b * QD_ + h * D_) * S_;        // +kp0 per chunk

  // ---- Q fragments in registers: A[m=l16][k=dc*32+quad*8+j], 2 m-tiles
  short8 aq[2][5];
#pragma unroll
  for (int mt = 0; mt < 2; ++mt) {
    const ushort_t* qrow =
        qws + ((size_t)(b * S_ + q0 + wid * 32 + mt * 16 + l16)) * QD_ + h * D_;
#pragma unroll
    for (int dc = 0; dc < 5; ++dc)
      aq[mt][dc] = *(const short8*)(qrow + dc * 32 + quad * 8);
  }

  // ---- prologue: stage chunk 0 (this wave's K granules first, then V)
#pragma unroll
  for (int jj = 0; jj < 6; ++jj) {
    const int j = jj * 4 + wid;
    if (j < 21) gload_lds16(kg + goff[jj], &smem[(size_t)j * 512]);
  }
#pragma unroll
  for (int jj = 5; jj < 11; ++jj) {
    const int j = jj * 4 + wid;
    if (j >= 21) gload_lds16(vg + goff[jj], &smem[(size_t)j * 512]);
  }

  f32x4 Oa[2][10];
#pragma unroll
  for (int mt = 0; mt < 2; ++mt)
#pragma unroll
    for (int nt = 0; nt < 10; ++nt) Oa[mt][nt] = {0.f, 0.f, 0.f, 0.f};
  float lpart[2][4] = {{0.f, 0.f, 0.f, 0.f}, {0.f, 0.f, 0.f, 0.f}};
  const float SC2 = SCALE * LOG2E;

  const int pswz = quad << 4;          // P write-side column XOR
  const int prsw = (l16 >> 2) << 4;    // P read-side column XOR

  for (int kp0 = 0; kp0 < S_; kp0 += TK) {
    // ---- Kt-valid barrier: wait only this wave's K loads (oldest 6 of 11);
    // V loads (the newest 5-6 vm ops) stay in flight across the barrier.
    asm volatile("s_waitcnt vmcnt(5)" ::: "memory");
    __builtin_amdgcn_sched_barrier(0);
    __builtin_amdgcn_s_barrier();
    __builtin_amdgcn_sched_barrier(0);

    // mask loads early: latency hides under the QK^T MFMA cluster
    float mv[4];
#pragma unroll
    for (int c = 0; c < 4; ++c)
      mv[c] = mask[b * S_ + kp0 + c * 16 + l16] * LOG2E;

    // ---- QK^T: S[32q][64k] as 2x4 16x16 C-frags over 5 d-chunks
    f32x4 s[2][4];
#pragma unroll
    for (int mt = 0; mt < 2; ++mt)
#pragma unroll
      for (int c = 0; c < 4; ++c) s[mt][c] = {0.f, 0.f, 0.f, 0.f};
    __builtin_amdgcn_s_setprio(1);
#pragma unroll
    for (int dc = 0; dc < 5; ++dc) {
      short8 bb[4];
#pragma unroll
      for (int c = 0; c < 4; ++c)
        bb[c] = *(const short8*)&Kt[(c * 16 + l16) * KTSTR + dc * 32 + quad * 8];
#pragma unroll
      for (int mt = 0; mt < 2; ++mt)
#pragma unroll
        for (int c = 0; c < 4; ++c)
          s[mt][c] = MFMA16(aq[mt][dc], bb[c], s[mt][c]);
    }
    __builtin_amdgcn_s_setprio(0);

    // ---- max-free softmax: p = exp2(s*SC2 + mv); per-lane l partials.
    // P[row][col] stored at col ^ (quad<<4)
    ushort_t* pw = Pp + wid * (32 * PSTR);
#pragma unroll
    for (int mt = 0; mt < 2; ++mt)
#pragma unroll
      for (int r = 0; r < 4; ++r) {
        const float p0 = exp2f(s[mt][0][r] * SC2 + mv[0]);
        const float p1 = exp2f(s[mt][1][r] * SC2 + mv[1]);
        const float p2 = exp2f(s[mt][2][r] * SC2 + mv[2]);
        const float p3 = exp2f(s[mt][3][r] * SC2 + mv[3]);
        lpart[mt][r] += (p0 + p1) + (p2 + p3);
        ushort_t* prow = pw + (mt * 16 + quad * 4 + r) * PSTR;
        prow[(pswz ^  0) + l16] = f2bf_fast(p0);
        prow[(pswz ^ 16) + l16] = f2bf_fast(p1);
        prow[(pswz ^ 32) + l16] = f2bf_fast(p2);
        prow[(pswz ^ 48) + l16] = f2bf_fast(p3);
      }

    // ---- PV A-frags from Pp (wave-private; LDS ops are in-order per wave)
    short8 ap[2][2];
#pragma unroll
    for (int mt = 0; mt < 2; ++mt) {
#pragma unroll
      for (int ks = 0; ks < 2; ++ks)
        ap[mt][ks] = *(const short8*)
            &Pp[wid * (32 * PSTR) + (mt * 16 + l16) * PSTR +
                ((ks * 32 + quad * 8) ^ prsw)];
    }

    // ---- Vt-valid barrier: full drain (V(t)+mask). Also guarantees every
    // wave finished its Kt reads -> Kt region is free after this point.
    __syncthreads();

    const int kn = kp0 + TK;
    // ---- stage K(t+1) now; its latency hides under the PV cluster
    if (kn < S_) {
      const ushort_t* kgn = kg + (size_t)kn * QD_;
#pragma unroll
      for (int jj = 0; jj < 6; ++jj) {
        const int j = jj * 4 + wid;
        if (j < 21) gload_lds16(kgn + goff[jj], &smem[(size_t)j * 512]);
      }
      __builtin_amdgcn_sched_barrier(0);   // pin issue before PV compute
    }

    // ---- PV: O[32q][160d] += P[32q][64k] * V[64k][160d] (2 k-steps)
    __builtin_amdgcn_s_setprio(1);
#pragma unroll
    for (int nt = 0; nt < 10; ++nt) {
      const short8 bv0 = *(const short8*)&Vt[(nt * 16 + l16) * VTSTR + quad * 8];
      const short8 bv1 = *(const short8*)&Vt[(nt * 16 + l16) * VTSTR + 32 + quad * 8];
#pragma unroll
      for (int mt = 0; mt < 2; ++mt) {
        Oa[mt][nt] = MFMA16(ap[mt][0], bv0, Oa[mt][nt]);
        Oa[mt][nt] = MFMA16(ap[mt][1], bv1, Oa[mt][nt]);
      }
    }
    __builtin_amdgcn_s_setprio(0);

    // ---- Vt-free barrier: RAW s_barrier, no vmcnt drain -> K(t+1) loads
    // stay in flight. All waves' Vt reads were consumed by PV MFMAs above.
    __builtin_amdgcn_sched_barrier(0);
    __builtin_amdgcn_s_barrier();
    __builtin_amdgcn_sched_barrier(0);

    // ---- stage V(t+1)
    if (kn < S_) {
      const ushort_t* vgn = vg + kn;
#pragma unroll
      for (int jj = 5; jj < 11; ++jj) {
        const int j = jj * 4 + wid;
        if (j >= 21) gload_lds16(vgn + goff[jj], &smem[(size_t)j * 512]);
      }
    }
  }

  // ---- final l reduction, normalize, write bf16 attn[b][s][h*160+d]
#pragma unroll
  for (int mt = 0; mt < 2; ++mt)
#pragma unroll
    for (int r = 0; r < 4; ++r) {
      const float l = row_sum16(lpart[mt][r]);
      const float inv = 1.f / l;
      const int qq = q0 + wid * 32 + mt * 16 + quad * 4 + r;
      ushort_t* orow = attn_out + ((size_t)(b * S_ + qq)) * QD_ + h * D_;
#pragma unroll
      for (int nt = 0; nt < 10; ++nt)
        orow[nt * 16 + l16] = f2bf_fast(Oa[mt][nt][r] * inv);
    }
}

// ---------------------------------------------------------------------------
// Workspace: Xt | Ct | Wq/Wk/Wv/Wout bf16 | q_ws | k_ws | v_ws | attn_ws
// ---------------------------------------------------------------------------
extern "C" void kernel_launch(void* const* d_in, const int* in_sizes, int n_in,
                              void* d_out, int out_size, void* d_ws, size_t ws_size,
                              hipStream_t stream) {
  const float* x    = (const float*)d_in[0];
  const float* c    = (const float*)d_in[1];
  const float* mask = (const float*)d_in[2];
  const float* Wq   = (const float*)d_in[3];
  const float* Wk   = (const float*)d_in[4];
  const float* Wv   = (const float*)d_in[5];
  const float* Wout = (const float*)d_in[6];
  const float* bout = (const float*)d_in[7];
  float* out = (float*)d_out;

  const size_t PB   = (size_t)S_ * QD_;     // 5,242,880 per batch
  const size_t NELT = (size_t)B_ * PB;      // 10,485,760
  const size_t WN   = (size_t)QD_ * QD_;    // 1,638,400

  ushort_t* Xt    = (ushort_t*)d_ws;
  ushort_t* Ct    = Xt + NELT;
  ushort_t* Wqb   = Ct + NELT;
  ushort_t* Wkb   = Wqb + WN;
  ushort_t* Wvb   = Wkb + WN;
  ushort_t* Woutb = Wvb + WN;
  ushort_t* q_ws  = Woutb + WN;
  ushort_t* k_ws  = q_ws + NELT;
  ushort_t* v_ws  = k_ws + NELT;
  ushort_t* attn_ws = v_ws + NELT;

  const dim3 tgrid(S_ / 32, QD_ / 32, 2 * B_);      // (128, 40, 4)
  transpose_cvt2<<<tgrid, 256, 0, stream>>>(x, c, Xt, Ct);
  cvt_w<<<dim3(WN / 1024, 4, 1), 256, 0, stream>>>(Wq, Wk, Wv, Wout,
                                                   Wqb, Wkb, Wvb, Woutb);

  // Fused Q/K/V projections: one 1920-block dispatch
  gemm_qkv<<<dim3(320, 1, 6), 256, 0, stream>>>(Xt, Ct, Wqb, Wkb, Wvb,
                                                q_ws, k_ws, v_ws);

  const dim3 agrid(S_ / TQ, H_, B_);                // (32, 8, 2)
  flash_attn_mfma<<<agrid, 256, 0, stream>>>(q_ws, k_ws, v_ws, mask, attn_ws);

  // Output projection (pipelined, mode 1: fp32 + bias)
  const dim3 gv(S_ / GBN, QD_ / GBM, B_);           // (32, 10, 2)
  gemm_mfma<<<gv, 256, 0, stream>>>(Woutb, attn_ws, out, bout,
                                    QD_, S_, QD_, 1, 0, PB, PB, 5, 8);
}